// Round 1
// baseline (248.301 us; speedup 1.0000x reference)
//
#include <hip/hip_runtime.h>
#include <hip/hip_bf16.h>

#define NQ 8192
#define NK 8192
#define DH 128
#define QBLK 32
#define KVBLK 64
#define NWAVES 8
#define LOG2E 1.44269504088896340736f

typedef __attribute__((ext_vector_type(8))) short short8;
typedef __attribute__((ext_vector_type(4))) short short4b;
typedef __attribute__((ext_vector_type(16))) float f32x16;

static __device__ __forceinline__ unsigned short f2bf(float x){
  unsigned u = __builtin_bit_cast(unsigned, x);
  u += 0x7FFFu + ((u >> 16) & 1u);
  return (unsigned short)(u >> 16);
}

// ---- preprocess: Q (scaled) and K fp32 -> bf16 -------------------------------
__global__ __launch_bounds__(256) void cast_qk_kernel(
    const float4* __restrict__ Q4, const float4* __restrict__ K4,
    ushort4* __restrict__ Qb4, ushort4* __restrict__ Kb4)
{
  const int n4 = NQ * DH / 4;
  int idx = blockIdx.x * 256 + threadIdx.x;
  if (idx < n4){
    const float s = 0.08838834764831844f; // 1/sqrt(128)
    float4 v = Q4[idx];
    Qb4[idx] = make_ushort4(f2bf(v.x * s), f2bf(v.y * s), f2bf(v.z * s), f2bf(v.w * s));
  } else {
    idx -= n4;
    float4 v = K4[idx];
    Kb4[idx] = make_ushort4(f2bf(v.x), f2bf(v.y), f2bf(v.z), f2bf(v.w));
  }
}

// ---- preprocess: V fp32 [NK][DH] -> V^T bf16 [DH][NK] ------------------------
__global__ __launch_bounds__(256) void transpose_v_kernel(
    const float* __restrict__ V, unsigned short* __restrict__ VT)
{
  __shared__ unsigned short t[64][65];
  const int n0 = (blockIdx.x >> 1) * 64;   // 128 n-tiles
  const int d0 = (blockIdx.x & 1) * 64;    // 2 d-tiles
  const int j  = threadIdx.x & 63;
  const int i0 = threadIdx.x >> 6;         // 0..3
#pragma unroll
  for (int i = i0; i < 64; i += 4)
    t[i][j] = f2bf(V[(size_t)(n0 + i) * DH + d0 + j]);
  __syncthreads();
#pragma unroll
  for (int i = i0; i < 64; i += 4)
    VT[(size_t)(d0 + i) * NK + n0 + j] = t[j][i];
}

// ---- main: flash attention, 8 waves split KV, LDS combine --------------------
__global__ __launch_bounds__(512, 1) void attn_kernel(
    const unsigned short* __restrict__ Qb,
    const unsigned short* __restrict__ Kb,
    const unsigned short* __restrict__ VT,
    float* __restrict__ Out)
{
  __shared__ float redbuf[4][QBLK][DH];   // 64 KiB
  __shared__ float smx[NWAVES][QBLK];
  __shared__ float slx[NWAVES][QBLK];

  const int tid  = threadIdx.x;
  const int wave = tid >> 6;
  const int lane = tid & 63;
  const int l32  = lane & 31;
  const int h    = lane >> 5;
  const int qbase = blockIdx.x * QBLK;

  // Q fragments (B operand of swapped QK^T): qf[m] covers d in [16m,16m+16)
  short8 qf[8];
  {
    const unsigned short* qp = Qb + (size_t)(qbase + l32) * DH + 8 * h;
#pragma unroll
    for (int m = 0; m < 8; ++m)
      qf[m] = *reinterpret_cast<const short8*>(qp + 16 * m);
  }

  f32x16 acc[4];
#pragma unroll
  for (int c = 0; c < 4; ++c)
#pragma unroll
    for (int r = 0; r < 16; ++r) acc[c][r] = 0.0f;

  float m_run = -3.0e38f;
  float l_run = 0.0f;

  for (int t = wave; t < NK / KVBLK; t += NWAVES){
    const int kvbase = t * KVBLK;

    // ---- S^T = K * Q^T  (two 32-kv sub-tiles)
    short8 kf[8];
    const unsigned short* kp = Kb + (size_t)(kvbase + l32) * DH + 8 * h;
#pragma unroll
    for (int m = 0; m < 8; ++m)
      kf[m] = *reinterpret_cast<const short8*>(kp + 16 * m);
    f32x16 S0;
#pragma unroll
    for (int r = 0; r < 16; ++r) S0[r] = 0.0f;
#pragma unroll
    for (int m = 0; m < 8; ++m)
      S0 = __builtin_amdgcn_mfma_f32_32x32x16_bf16(kf[m], qf[m], S0, 0, 0, 0);

    const unsigned short* kp2 = kp + 32 * DH;
#pragma unroll
    for (int m = 0; m < 8; ++m)
      kf[m] = *reinterpret_cast<const short8*>(kp2 + 16 * m);
    f32x16 S1;
#pragma unroll
    for (int r = 0; r < 16; ++r) S1[r] = 0.0f;
#pragma unroll
    for (int m = 0; m < 8; ++m)
      S1 = __builtin_amdgcn_mfma_f32_32x32x16_bf16(kf[m], qf[m], S1, 0, 0, 0);

    // ---- online softmax; lane owns q = l32 (duplicated across halves)
    float pm = -3.0e38f;
#pragma unroll
    for (int r = 0; r < 16; ++r){
      pm = fmaxf(pm, S0[r]);
      pm = fmaxf(pm, S1[r]);
    }
    pm = fmaxf(pm, __shfl_xor(pm, 32, 64));

    if (!__all(pm <= m_run + 8.0f)){   // defer-max (T13)
      float mnew = fmaxf(m_run, pm);
      float rs = exp2f((m_run - mnew) * LOG2E);
      l_run *= rs;
      m_run = mnew;
#pragma unroll
      for (int r = 0; r < 16; ++r){
        float f = __shfl(rs, (r & 3) + 8 * (r >> 2) + 4 * h, 64);
#pragma unroll
        for (int c = 0; c < 4; ++c) acc[c][r] *= f;
      }
    }

    float p0[16], p1[16];
    float psum = 0.0f;
#pragma unroll
    for (int r = 0; r < 16; ++r){
      p0[r] = exp2f((S0[r] - m_run) * LOG2E);
      p1[r] = exp2f((S1[r] - m_run) * LOG2E);
      psum += p0[r] + p1[r];
    }
    psum += __shfl_xor(psum, 32, 64);
    l_run += psum;

    // P fragments: S^T reg r holds kv = (r&3)+8*(r>>2)+4h  ->  A-frag elems
    short8 pa[4];
#pragma unroll
    for (int e = 0; e < 8; ++e){
      pa[0][e] = (short)f2bf(p0[e]);
      pa[1][e] = (short)f2bf(p0[8 + e]);
      pa[2][e] = (short)f2bf(p1[e]);
      pa[3][e] = (short)f2bf(p1[8 + e]);
    }

    // ---- PV: O[q][d] += P * V ; V^T frag matches P's (h,e)->kv map
#pragma unroll
    for (int c = 0; c < 4; ++c){
      const unsigned short* vp = VT + (size_t)(32 * c + l32) * NK + kvbase + 4 * h;
#pragma unroll
      for (int mm = 0; mm < 4; ++mm){
        union { short4b h4[2]; short8 v8; } u;
        u.h4[0] = *reinterpret_cast<const short4b*>(vp + 16 * mm);
        u.h4[1] = *reinterpret_cast<const short4b*>(vp + 16 * mm + 8);
        acc[c] = __builtin_amdgcn_mfma_f32_32x32x16_bf16(pa[mm], u.v8, acc[c], 0, 0, 0);
      }
    }
  }

  // ---- combine the 8 waves' partials
  if (lane < 32){ smx[wave][lane] = m_run; slx[wave][lane] = l_run; }
  __syncthreads();

  float M = -3.0e38f;
#pragma unroll
  for (int w = 0; w < NWAVES; ++w) M = fmaxf(M, smx[w][l32]);
  float L = 0.0f;
#pragma unroll
  for (int w = 0; w < NWAVES; ++w)
    L += slx[w][l32] * exp2f((smx[w][l32] - M) * LOG2E);
  const float beta = exp2f((m_run - M) * LOG2E) / L;

#pragma unroll
  for (int r = 0; r < 16; ++r){
    float f = __shfl(beta, (r & 3) + 8 * (r >> 2) + 4 * h, 64);
#pragma unroll
    for (int c = 0; c < 4; ++c) acc[c][r] *= f;
  }

  // tree reduction: 8 -> 4 -> 2 -> 1
  if (wave & 1){
#pragma unroll
    for (int c = 0; c < 4; ++c)
#pragma unroll
      for (int r = 0; r < 16; ++r)
        redbuf[wave >> 1][(r & 3) + 8 * (r >> 2) + 4 * h][32 * c + l32] = acc[c][r];
  }
  __syncthreads();
  if (!(wave & 1)){
#pragma unroll
    for (int c = 0; c < 4; ++c)
#pragma unroll
      for (int r = 0; r < 16; ++r)
        acc[c][r] += redbuf[wave >> 1][(r & 3) + 8 * (r >> 2) + 4 * h][32 * c + l32];
  }
  __syncthreads();
  if ((wave & 3) == 2){
#pragma unroll
    for (int c = 0; c < 4; ++c)
#pragma unroll
      for (int r = 0; r < 16; ++r)
        redbuf[wave >> 2][(r & 3) + 8 * (r >> 2) + 4 * h][32 * c + l32] = acc[c][r];
  }
  __syncthreads();
  if ((wave & 3) == 0){
#pragma unroll
    for (int c = 0; c < 4; ++c)
#pragma unroll
      for (int r = 0; r < 16; ++r)
        acc[c][r] += redbuf[wave >> 2][(r & 3) + 8 * (r >> 2) + 4 * h][32 * c + l32];
  }
  __syncthreads();
  if (wave == 4){
#pragma unroll
    for (int c = 0; c < 4; ++c)
#pragma unroll
      for (int r = 0; r < 16; ++r)
        redbuf[0][(r & 3) + 8 * (r >> 2) + 4 * h][32 * c + l32] = acc[c][r];
  }
  __syncthreads();
  if (wave == 0){
#pragma unroll
    for (int c = 0; c < 4; ++c)
#pragma unroll
      for (int r = 0; r < 16; ++r){
        const int q = (r & 3) + 8 * (r >> 2) + 4 * h;
        float v = acc[c][r] + redbuf[0][q][32 * c + l32];
        Out[(size_t)(qbase + q) * DH + 32 * c + l32] = v;
      }
  }
}

extern "C" void kernel_launch(void* const* d_in, const int* in_sizes, int n_in,
                              void* d_out, int out_size, void* d_ws, size_t ws_size,
                              hipStream_t stream)
{
  const float* Q = (const float*)d_in[0];
  const float* K = (const float*)d_in[1];
  const float* V = (const float*)d_in[2];
  unsigned short* Qb = (unsigned short*)d_ws;                 // 2 MiB
  unsigned short* Kb = Qb + (size_t)NQ * DH;                  // 2 MiB
  unsigned short* VT = Kb + (size_t)NK * DH;                  // 2 MiB (V^T)
  float* Out = (float*)d_out;

  cast_qk_kernel<<<2 * NQ * DH / 4 / 256, 256, 0, stream>>>(
      (const float4*)Q, (const float4*)K, (ushort4*)Qb, (ushort4*)Kb);
  transpose_v_kernel<<<(NK / 64) * (DH / 64), 256, 0, stream>>>(V, VT);
  attn_kernel<<<NQ / QBLK, 512, 0, stream>>>(Qb, Kb, VT, Out);
}

// Round 2
// 125.228 us; speedup vs baseline: 1.9828x; 1.9828x over previous
//
#include <hip/hip_runtime.h>
#include <hip/hip_bf16.h>

#define NQ 8192
#define NK 8192
#define DH 128
#define KVBLK 64
#define SLICES 8
#define TILES (NK / SLICES / KVBLK)   // 16 tiles of 64 kv per block
#define LOG2E 1.44269504088896340736f

typedef __attribute__((ext_vector_type(8))) short short8;
typedef __attribute__((ext_vector_type(8))) unsigned short ushort8v;
typedef __attribute__((ext_vector_type(16))) float f32x16;

static __device__ __forceinline__ unsigned short f2bf(float x){
  unsigned u = __builtin_bit_cast(unsigned, x);
  u += 0x7FFFu + ((u >> 16) & 1u);
  return (unsigned short)(u >> 16);
}

static __device__ __forceinline__ void gload_lds16(const void* g, void* l){
  __builtin_amdgcn_global_load_lds((const __attribute__((address_space(1))) void*)g,
                                   (__attribute__((address_space(3))) void*)l,
                                   16, 0, 0);
}

// ---- preprocess: Q fp32 -> bf16 row-major, scaled by 1/sqrt(128) -------------
__global__ __launch_bounds__(512) void prep_q(const float4* __restrict__ Q4,
                                              ushort8v* __restrict__ Qb8)
{
  int i = blockIdx.x * 512 + threadIdx.x;      // 131072 groups of 8
  const float s = 0.08838834764831844f;
  float4 a = Q4[2 * i], b = Q4[2 * i + 1];
  ushort8v o;
  o[0]=f2bf(a.x*s); o[1]=f2bf(a.y*s); o[2]=f2bf(a.z*s); o[3]=f2bf(a.w*s);
  o[4]=f2bf(b.x*s); o[5]=f2bf(b.y*s); o[6]=f2bf(b.z*s); o[7]=f2bf(b.w*s);
  Qb8[i] = o;
}

// ---- preprocess: K,V fp32 -> tiled / permuted / XOR-swizzled bf16 images -----
// K tile t (16KB): bf16 K[kv][d] at byte (kv*256 + d*2) ^ ((kv&7)<<4)
// V tile t (16KB): bf16 V^T, slot j = mm*16+h*8+p*4+e holds kv = mm*16+p*8+h*4+e,
//                  at byte (d*128 + j*2) ^ ((d&7)<<4)
__global__ __launch_bounds__(512) void prep_kv(const float* __restrict__ K,
                                               const float* __restrict__ V,
                                               unsigned char* __restrict__ Kt,
                                               unsigned char* __restrict__ Vt)
{
  __shared__ float vs[KVBLK * DH];             // 32 KiB
  const int tile = blockIdx.x;
  const int tid  = threadIdx.x;

  // stage V tile f32 into LDS (coalesced)
  const float4* Vg = (const float4*)(V + (size_t)tile * KVBLK * DH);
  float4* vs4 = (float4*)vs;
#pragma unroll
  for (int k = 0; k < 4; ++k) vs4[tid + k * 512] = Vg[tid + k * 512];

  // K: 1024 tasks of (kv, d0)
  unsigned char* Ktb = Kt + (size_t)tile * 16384;
  const float* Kg = K + (size_t)tile * KVBLK * DH;
#pragma unroll
  for (int k = 0; k < 2; ++k){
    int task = tid + k * 512;
    int kv = task >> 4, d0 = (task & 15) * 8;
    const float4* p = (const float4*)(Kg + kv * DH + d0);
    float4 a = p[0], b = p[1];
    ushort8v o;
    o[0]=f2bf(a.x); o[1]=f2bf(a.y); o[2]=f2bf(a.z); o[3]=f2bf(a.w);
    o[4]=f2bf(b.x); o[5]=f2bf(b.y); o[6]=f2bf(b.z); o[7]=f2bf(b.w);
    int addr = (kv * 256 + d0 * 2) ^ ((kv & 7) << 4);
    *(ushort8v*)(Ktb + addr) = o;
  }
  __syncthreads();

  // V: 1024 tasks of (d, mm, h)
  unsigned char* Vtb = Vt + (size_t)tile * 16384;
#pragma unroll
  for (int k = 0; k < 2; ++k){
    int task = tid + k * 512;
    int d = task >> 3, mm = (task >> 1) & 3, h = task & 1;
    int kvb = mm * 16 + h * 4;
    ushort8v o;
    o[0]=f2bf(vs[(kvb+0)*DH + d]); o[1]=f2bf(vs[(kvb+1)*DH + d]);
    o[2]=f2bf(vs[(kvb+2)*DH + d]); o[3]=f2bf(vs[(kvb+3)*DH + d]);
    o[4]=f2bf(vs[(kvb+8)*DH + d]); o[5]=f2bf(vs[(kvb+9)*DH + d]);
    o[6]=f2bf(vs[(kvb+10)*DH + d]); o[7]=f2bf(vs[(kvb+11)*DH + d]);
    int addr = (d * 128 + (mm * 16 + h * 8) * 2) ^ ((d & 7) << 4);
    *(ushort8v*)(Vtb + addr) = o;
  }
}

// ---- main: 8 waves x 32 q-rows each, shared LDS K/V, double-buffered ---------
__global__ __launch_bounds__(512, 2) void attn_kernel(
    const unsigned short* __restrict__ Qb,
    const unsigned char* __restrict__ Kt,
    const unsigned char* __restrict__ Vt,
    float* __restrict__ Opart, float* __restrict__ Mpart, float* __restrict__ Lpart)
{
  __shared__ unsigned char lK[2][16384];
  __shared__ unsigned char lV[2][16384];

  const int tid  = threadIdx.x;
  const int wave = tid >> 6;
  const int lane = tid & 63;
  const int l32  = lane & 31;
  const int h    = lane >> 5;
  const int bq    = blockIdx.x >> 3;
  const int slice = blockIdx.x & 7;
  const int qrow0 = bq * 256 + wave * 32;
  const size_t tile0 = (size_t)slice * TILES;
  const int kx = (l32 & 7) << 4;

  // Q fragments: qf[m] covers d in [16m+8h, +8)
  short8 qf[8];
  {
    const unsigned short* qp = Qb + (size_t)(qrow0 + l32) * DH + 8 * h;
#pragma unroll
    for (int m = 0; m < 8; ++m) qf[m] = *(const short8*)(qp + 16 * m);
  }

  f32x16 acc[4];
#pragma unroll
  for (int c = 0; c < 4; ++c)
#pragma unroll
    for (int r = 0; r < 16; ++r) acc[c][r] = 0.0f;
  float m_run = -3.0e38f, l_run = 0.0f;

  // stage: waves 0-3 copy K tile, waves 4-7 copy V tile (16KB each, 16B chunks)
  auto stage = [&](int buf, int t){
    if (wave < 4){
      const unsigned char* g = Kt + (tile0 + t) * 16384 + (wave * 64 + lane) * 16;
      unsigned char* l = &lK[buf][(wave * 64 + lane) * 16];
#pragma unroll
      for (int j = 0; j < 4; ++j) gload_lds16(g + j * 4096, l + j * 4096);
    } else {
      const unsigned char* g = Vt + (tile0 + t) * 16384 + ((wave - 4) * 64 + lane) * 16;
      unsigned char* l = &lV[buf][((wave - 4) * 64 + lane) * 16];
#pragma unroll
      for (int j = 0; j < 4; ++j) gload_lds16(g + j * 4096, l + j * 4096);
    }
  };

  stage(0, 0);
  __syncthreads();
  int cur = 0;

  for (int t = 0; t < TILES; ++t){
    if (t + 1 < TILES) stage(cur ^ 1, t + 1);

    const unsigned char* Kb = lK[cur];
    const unsigned char* Vb = lV[cur];

    // ---- S^T = K * Q^T : two interleaved chains over the 64-kv tile
    f32x16 S0, S1;
#pragma unroll
    for (int r = 0; r < 16; ++r){ S0[r] = 0.0f; S1[r] = 0.0f; }
    __builtin_amdgcn_s_setprio(1);
#pragma unroll
    for (int m = 0; m < 8; ++m){
      short8 a = *(const short8*)(Kb + l32 * 256 + ((32 * m + 16 * h) ^ kx));
      short8 b = *(const short8*)(Kb + 8192 + l32 * 256 + ((32 * m + 16 * h) ^ kx));
      S0 = __builtin_amdgcn_mfma_f32_32x32x16_bf16(a, qf[m], S0, 0, 0, 0);
      S1 = __builtin_amdgcn_mfma_f32_32x32x16_bf16(b, qf[m], S1, 0, 0, 0);
    }
    __builtin_amdgcn_s_setprio(0);

    // ---- online softmax (lane owns q-row l32, duplicated across halves)
    float pm = -3.0e38f;
#pragma unroll
    for (int r = 0; r < 16; ++r){
      pm = fmaxf(pm, S0[r]);
      pm = fmaxf(pm, S1[r]);
    }
    pm = fmaxf(pm, __shfl_xor(pm, 32, 64));

    if (!__all(pm <= m_run + 8.0f)){      // defer-max (T13)
      float mnew = fmaxf(m_run, pm);
      float rs = exp2f((m_run - mnew) * LOG2E);
      l_run *= rs; m_run = mnew;
#pragma unroll
      for (int r = 0; r < 16; ++r){
        float f = __shfl(rs, (r & 3) + 8 * (r >> 2) + 4 * h, 64);
#pragma unroll
        for (int c = 0; c < 4; ++c) acc[c][r] *= f;
      }
    }

    float p0[16], p1[16], psum = 0.0f;
#pragma unroll
    for (int r = 0; r < 16; ++r){
      p0[r] = exp2f((S0[r] - m_run) * LOG2E);
      p1[r] = exp2f((S1[r] - m_run) * LOG2E);
      psum += p0[r] + p1[r];
    }
    psum += __shfl_xor(psum, 32, 64);
    l_run += psum;

    short8 pa[4];
#pragma unroll
    for (int e = 0; e < 8; ++e){
      pa[0][e] = (short)f2bf(p0[e]);
      pa[1][e] = (short)f2bf(p0[8 + e]);
      pa[2][e] = (short)f2bf(p1[e]);
      pa[3][e] = (short)f2bf(p1[8 + e]);
    }

    // ---- PV: acc[c] += P * V, V B-frags are single b128 reads (permuted tile)
    __builtin_amdgcn_s_setprio(1);
#pragma unroll
    for (int c = 0; c < 4; ++c){
      const unsigned char* vrow = Vb + (32 * c + l32) * 128;
#pragma unroll
      for (int mm = 0; mm < 4; ++mm){
        short8 vfr = *(const short8*)(vrow + ((mm * 32 + 16 * h) ^ kx));
        acc[c] = __builtin_amdgcn_mfma_f32_32x32x16_bf16(pa[mm], vfr, acc[c], 0, 0, 0);
      }
    }
    __builtin_amdgcn_s_setprio(0);

    __syncthreads();     // drain own stage loads (vmcnt) + all waves done with buf
    cur ^= 1;
  }

  // ---- write per-slice partials
  if (lane < 32){
    Mpart[(size_t)slice * NQ + qrow0 + lane] = m_run;
    Lpart[(size_t)slice * NQ + qrow0 + lane] = l_run;
  }
#pragma unroll
  for (int c = 0; c < 4; ++c)
#pragma unroll
    for (int r = 0; r < 16; ++r){
      int q = qrow0 + (r & 3) + 8 * (r >> 2) + 4 * h;
      Opart[((size_t)slice * NQ + q) * DH + 32 * c + l32] = acc[c][r];
    }
}

// ---- combine the 8 kv-slice partials per q row --------------------------------
__global__ __launch_bounds__(256) void combine_kernel(
    const float4* __restrict__ Op4, const float* __restrict__ Mp,
    const float* __restrict__ Lp, float4* __restrict__ Out4)
{
  const int q  = blockIdx.x * 8 + (threadIdx.x >> 5);
  const int dd = threadIdx.x & 31;

  float ms[SLICES], M = -3.0e38f;
#pragma unroll
  for (int s = 0; s < SLICES; ++s){ ms[s] = Mp[s * NQ + q]; M = fmaxf(M, ms[s]); }
  float L = 0.0f, w[SLICES];
#pragma unroll
  for (int s = 0; s < SLICES; ++s){
    w[s] = exp2f((ms[s] - M) * LOG2E);
    L += Lp[s * NQ + q] * w[s];
  }
  float4 o = make_float4(0.f, 0.f, 0.f, 0.f);
#pragma unroll
  for (int s = 0; s < SLICES; ++s){
    float4 v = Op4[((size_t)s * NQ + q) * 32 + dd];
    o.x += w[s] * v.x; o.y += w[s] * v.y; o.z += w[s] * v.z; o.w += w[s] * v.w;
  }
  float inv = 1.0f / L;
  Out4[(size_t)q * 32 + dd] = make_float4(o.x * inv, o.y * inv, o.z * inv, o.w * inv);
}

extern "C" void kernel_launch(void* const* d_in, const int* in_sizes, int n_in,
                              void* d_out, int out_size, void* d_ws, size_t ws_size,
                              hipStream_t stream)
{
  const float* Q = (const float*)d_in[0];
  const float* K = (const float*)d_in[1];
  const float* V = (const float*)d_in[2];

  unsigned char* ws = (unsigned char*)d_ws;
  const size_t MB2 = (size_t)NQ * DH * 2;            // 2 MiB
  unsigned short* Qb = (unsigned short*)ws;          // 2 MiB
  unsigned char*  Kt = ws + MB2;                     // 2 MiB (tiled swizzled)
  unsigned char*  Vt = ws + 2 * MB2;                 // 2 MiB (tiled permuted swizzled)
  float* Mp = (float*)(ws + 3 * MB2);                // 256 KiB
  float* Lp = Mp + (size_t)SLICES * NQ;              // 256 KiB
  float* Op = Lp + (size_t)SLICES * NQ;              // 32 MiB

  prep_q<<<NQ * DH / 8 / 512, 512, 0, stream>>>((const float4*)Q, (ushort8v*)Qb);
  prep_kv<<<NK / KVBLK, 512, 0, stream>>>(K, V, Kt, Vt);
  attn_kernel<<<(NQ / 256) * SLICES, 512, 0, stream>>>(Qb, Kt, Vt, Op, Mp, Lp);
  combine_kernel<<<NQ / 8, 256, 0, stream>>>((const float4*)Op, Mp, Lp, (float4*)d_out);
}